// Round 1
// baseline (546.919 us; speedup 1.0000x reference)
//
#include <hip/hip_runtime.h>
#include <stdint.h>

// LeNet5-XNOR fused pipeline for MI355X.
// Stages:
//  conv1 (fp32 5x5, 1->20) -> BN(batch mean only; sign test is conv>mean)
//  -> relu+pool2x2+sign => 20-bit channel mask per (n, 14x14 pos)
//  conv2 (binary, 20->50, 5x5) via popcount -> pool+sign => int8 {-1,0,1}
//  linear (binary 1250->500) via dual-mask popcount -> clip -> fc(500->10)

#define NIMG 8192
#define CNT1 (8192.0 * 784.0)

// ---------------- workspace layout ----------------
// 0       : 20 doubles  (channel sums)
// 256     : 20 floats   (means)
// 512     : 1250 u32    (packed conv2 weight sign masks, bit ic)
// 5632    : 500 floats  (alpha_l)
// 7680    : 500*20 u64  (packed sign(lin_w) rows)
// 87808   : 8192*196 u32 (stage-1 channel masks)
// 6510336 : 8192*1250 s8 (stage-2 signs)
// total ~16.75 MB

__global__ __launch_bounds__(256) void prep_w2_k(const float* __restrict__ w2,
                                                 uint32_t* __restrict__ wp2) {
  int idx = blockIdx.x * 256 + threadIdx.x;
  if (idx >= 1250) return;
  int oc = idx / 25, k = idx % 25;
  uint32_t m = 0;
  for (int ic = 0; ic < 20; ++ic)
    if (w2[(oc * 20 + ic) * 25 + k] > 0.f) m |= (1u << ic);
  wp2[idx] = m;
}

__global__ __launch_bounds__(64) void prep_lin_k(const float* __restrict__ lw,
                                                 unsigned long long* __restrict__ lwp,
                                                 float* __restrict__ alpha) {
  int j = blockIdx.x, t = threadIdx.x;
  float pa = 0.f;
  for (int k = t; k < 1250; k += 64) pa += fabsf(lw[j * 1250 + k]);
  for (int o = 32; o > 0; o >>= 1) pa += __shfl_down(pa, o, 64);
  if (t == 0) alpha[j] = pa / 1250.0f;
  if (t < 20) {
    unsigned long long m = 0;
    int base = j * 1250 + t * 64;
    int lim = 1250 - t * 64; if (lim > 64) lim = 64;
    for (int b = 0; b < lim; ++b)
      if (lw[base + b] > 0.f) m |= (1ull << b);
    lwp[j * 20 + t] = m;
  }
}

__global__ __launch_bounds__(256) void conv1_stats_k(const float* __restrict__ x,
                                                     const float* __restrict__ w1,
                                                     double* __restrict__ stats) {
  __shared__ float img[1024];
  __shared__ float wsh[500];
  __shared__ double red[4][20];
  int n = blockIdx.x, tid = threadIdx.x;
  for (int i = tid; i < 1024; i += 256) img[i] = x[n * 1024 + i];
  for (int i = tid; i < 500; i += 256) wsh[i] = w1[i];
  __syncthreads();
  double acc[20];
#pragma unroll
  for (int c = 0; c < 20; ++c) acc[c] = 0.0;
  if (tid < 196) {
    int py = tid / 14, px = tid % 14;
    float p[6][6];
#pragma unroll
    for (int r = 0; r < 6; ++r)
#pragma unroll
      for (int cc = 0; cc < 6; ++cc)
        p[r][cc] = img[(2 * py + r) * 32 + 2 * px + cc];
    for (int c = 0; c < 20; ++c) {
      float s0 = 0.f, s1 = 0.f, s2 = 0.f, s3 = 0.f;
#pragma unroll
      for (int ky = 0; ky < 5; ++ky)
#pragma unroll
        for (int kx = 0; kx < 5; ++kx) {
          float wv = wsh[c * 25 + ky * 5 + kx];
          s0 += p[ky][kx] * wv;
          s1 += p[ky][kx + 1] * wv;
          s2 += p[ky + 1][kx] * wv;
          s3 += p[ky + 1][kx + 1] * wv;
        }
      acc[c] += (double)((s0 + s1) + (s2 + s3));
    }
  }
  int wid = tid >> 6, lane = tid & 63;
#pragma unroll
  for (int c = 0; c < 20; ++c) {
    double v = acc[c];
    for (int o = 32; o > 0; o >>= 1) v += __shfl_down(v, o, 64);
    if (lane == 0) red[wid][c] = v;
  }
  __syncthreads();
  if (tid < 20) {
    double t = red[0][tid] + red[1][tid] + red[2][tid] + red[3][tid];
    atomicAdd(&stats[tid], t);
  }
}

__global__ void finalize_mean_k(const double* __restrict__ stats,
                                float* __restrict__ mean) {
  int c = threadIdx.x;
  if (c < 20) mean[c] = (float)(stats[c] / CNT1);
}

__global__ __launch_bounds__(256) void conv1_sign_k(const float* __restrict__ x,
                                                    const float* __restrict__ w1,
                                                    const float* __restrict__ mean,
                                                    uint32_t* __restrict__ b1p) {
  __shared__ float img[1024];
  __shared__ float wsh[500];
  __shared__ float msh[20];
  int n = blockIdx.x, tid = threadIdx.x;
  for (int i = tid; i < 1024; i += 256) img[i] = x[n * 1024 + i];
  for (int i = tid; i < 500; i += 256) wsh[i] = w1[i];
  if (tid < 20) msh[tid] = mean[tid];
  __syncthreads();
  if (tid < 196) {
    int py = tid / 14, px = tid % 14;
    float p[6][6];
#pragma unroll
    for (int r = 0; r < 6; ++r)
#pragma unroll
      for (int cc = 0; cc < 6; ++cc)
        p[r][cc] = img[(2 * py + r) * 32 + 2 * px + cc];
    uint32_t mask = 0;
    for (int c = 0; c < 20; ++c) {
      float s0 = 0.f, s1 = 0.f, s2 = 0.f, s3 = 0.f;
#pragma unroll
      for (int ky = 0; ky < 5; ++ky)
#pragma unroll
        for (int kx = 0; kx < 5; ++kx) {
          float wv = wsh[c * 25 + ky * 5 + kx];
          s0 += p[ky][kx] * wv;
          s1 += p[ky][kx + 1] * wv;
          s2 += p[ky + 1][kx] * wv;
          s3 += p[ky + 1][kx + 1] * wv;
        }
      float m = msh[c];
      if (s0 > m || s1 > m || s2 > m || s3 > m) mask |= (1u << c);
    }
    b1p[n * 196 + tid] = mask;
  }
}

__global__ __launch_bounds__(256) void conv2_k(const uint32_t* __restrict__ b1p,
                                               const uint32_t* __restrict__ wp2,
                                               signed char* __restrict__ s2) {
  __shared__ uint32_t bm[196];
  __shared__ int sp[196];
  __shared__ int sumpc[100];
  __shared__ uint32_t wsh[1250];
  int n = blockIdx.x, tid = threadIdx.x;
  if (tid < 196) bm[tid] = b1p[n * 196 + tid];
  for (int i = tid; i < 1250; i += 256) wsh[i] = wp2[i];
  __syncthreads();
  if (tid < 196) sp[tid] = __popc(bm[tid]);
  __syncthreads();
  if (tid < 100) {
    int y = tid / 10, xx = tid % 10, s = 0;
#pragma unroll
    for (int ky = 0; ky < 5; ++ky)
#pragma unroll
      for (int kx = 0; kx < 5; ++kx)
        s += sp[(y + ky) * 14 + xx + kx];
    sumpc[tid] = s;
  }
  __syncthreads();
  for (int item = tid; item < 1250; item += 256) {
    int oc = item / 25, p = item % 25, py = p / 5, px = p % 5;
    uint32_t w[25];
#pragma unroll
    for (int i = 0; i < 25; ++i) w[i] = wsh[oc * 25 + i];
    int best = -1000000;
#pragma unroll
    for (int dy = 0; dy < 2; ++dy)
#pragma unroll
      for (int dx = 0; dx < 2; ++dx) {
        int y = 2 * py + dy, xx = 2 * px + dx;
        int a = 0;
#pragma unroll
        for (int ky = 0; ky < 5; ++ky)
#pragma unroll
          for (int kx = 0; kx < 5; ++kx)
            a += __popc(w[ky * 5 + kx] & bm[(y + ky) * 14 + xx + kx]);
        a = 2 * a - sumpc[y * 10 + xx];
        if (a > best) best = a;
      }
    s2[n * 1250 + item] = (signed char)((best > 0) - (best < 0));
  }
}

__global__ __launch_bounds__(256) void linear_fc_k(const signed char* __restrict__ s2,
                                                   const unsigned long long* __restrict__ lwp,
                                                   const float* __restrict__ alpha,
                                                   const float* __restrict__ fcw,
                                                   const float* __restrict__ fcb,
                                                   float* __restrict__ out) {
  __shared__ signed char ssh[1280];
  __shared__ unsigned long long Pm[20], Nm[20];
  __shared__ int cnts[2];
  __shared__ float hsh[500];
  __shared__ float fr[160];
  int n = blockIdx.x, tid = threadIdx.x;
  for (int i = tid; i < 1280; i += 256)
    ssh[i] = (i < 1250) ? s2[n * 1250 + i] : (signed char)0;
  __syncthreads();
  if (tid < 20) {
    unsigned long long P = 0, Ng = 0;
    for (int b = 0; b < 64; ++b) {
      signed char v = ssh[tid * 64 + b];
      if (v > 0) P |= (1ull << b);
      if (v < 0) Ng |= (1ull << b);
    }
    Pm[tid] = P; Nm[tid] = Ng;
  }
  __syncthreads();
  if (tid == 0) {
    int cp = 0, cn = 0;
    for (int i = 0; i < 20; ++i) { cp += __popcll(Pm[i]); cn += __popcll(Nm[i]); }
    cnts[0] = cp; cnts[1] = cn;
  }
  __syncthreads();
  for (int j = tid; j < 500; j += 256) {
    const unsigned long long* W = lwp + j * 20;
    int a = 0, b = 0;
#pragma unroll
    for (int i = 0; i < 20; ++i) {
      unsigned long long w = W[i];
      a += __popcll(w & Pm[i]);
      b += __popcll(w & Nm[i]);
    }
    int dot = 2 * (a - b) - cnts[0] + cnts[1];
    float y = alpha[j] * (float)dot;
    y = fminf(1.0f, fmaxf(-1.0f, y));
    hsh[j] = y;
  }
  __syncthreads();
  if (tid < 160) {
    int o = tid >> 4, l = tid & 15;
    float pa = 0.f;
    for (int j = l; j < 500; j += 16) pa += hsh[j] * fcw[o * 500 + j];
    fr[tid] = pa;
  }
  __syncthreads();
  if (tid < 10) {
    float s = fcb[tid];
    for (int l = 0; l < 16; ++l) s += fr[tid * 16 + l];
    out[n * 10 + tid] = s;
  }
}

extern "C" void kernel_launch(void* const* d_in, const int* in_sizes, int n_in,
                              void* d_out, int out_size, void* d_ws, size_t ws_size,
                              hipStream_t stream) {
  const float* x   = (const float*)d_in[0];
  const float* w1  = (const float*)d_in[1];
  const float* w2  = (const float*)d_in[2];
  const float* lw  = (const float*)d_in[3];
  const float* fcw = (const float*)d_in[4];
  const float* fcb = (const float*)d_in[5];
  float* out = (float*)d_out;
  char* ws = (char*)d_ws;

  double*   stats = (double*)(ws + 0);
  float*    mean  = (float*)(ws + 256);
  uint32_t* wp2   = (uint32_t*)(ws + 512);
  float*    alpha = (float*)(ws + 5632);
  unsigned long long* lwp = (unsigned long long*)(ws + 7680);
  uint32_t* b1p   = (uint32_t*)(ws + 87808);
  signed char* s2 = (signed char*)(ws + 6510336);

  hipMemsetAsync(stats, 0, 20 * sizeof(double), stream);
  prep_w2_k<<<5, 256, 0, stream>>>(w2, wp2);
  prep_lin_k<<<500, 64, 0, stream>>>(lw, lwp, alpha);
  conv1_stats_k<<<NIMG, 256, 0, stream>>>(x, w1, stats);
  finalize_mean_k<<<1, 32, 0, stream>>>(stats, mean);
  conv1_sign_k<<<NIMG, 256, 0, stream>>>(x, w1, mean, b1p);
  conv2_k<<<NIMG, 256, 0, stream>>>(b1p, wp2, s2);
  linear_fc_k<<<NIMG, 256, 0, stream>>>(s2, lwp, alpha, fcw, fcb, out);
}

// Round 2
// 308.101 us; speedup vs baseline: 1.7751x; 1.7751x over previous
//
#include <hip/hip_runtime.h>
#include <stdint.h>

// LeNet5-XNOR fused pipeline, round 2.
// Key change vs round 1: BN mean computed analytically from the summed image
// (mean is linear in x), deleting the 164us conv1_stats pass. conv1_sign is
// wave-dense (thread = (n, pooled pos), SGPR weights). conv2+linear+fc fused
// into one kernel per image with register-resident bm patches.

#define NIMG 8192

// ---------------- workspace layout ----------------
// 0      : 1024 f32   T (summed image)
// 4096   : 20 f32     mean
// 4224   : 1250 u32   packed conv2 weight sign masks (bit = ic)
// 9344   : 500 f32    alpha_l
// 11392  : 500*20 u64 packed sign(lin_w) rows   (16B aligned)
// 91392  : 8192*196 u32 stage-1 channel masks
// total ~6.5 MB

__global__ __launch_bounds__(64) void prep_k(const float* __restrict__ lw,
                                             const float* __restrict__ w2,
                                             unsigned long long* __restrict__ lwp,
                                             float* __restrict__ alpha,
                                             uint32_t* __restrict__ wp2) {
  int b = blockIdx.x, t = threadIdx.x;
  if (b < 500) {
    int j = b;
    float pa = 0.f;
    for (int k = t; k < 1250; k += 64) pa += fabsf(lw[j * 1250 + k]);
    for (int o = 32; o > 0; o >>= 1) pa += __shfl_down(pa, o, 64);
    if (t == 0) alpha[j] = pa / 1250.0f;
    if (t < 20) {
      unsigned long long m = 0;
      int base = j * 1250 + t * 64;
      int lim = 1250 - t * 64; if (lim > 64) lim = 64;
      for (int bb = 0; bb < lim; ++bb)
        if (lw[base + bb] > 0.f) m |= (1ull << bb);
      lwp[j * 20 + t] = m;
    }
  } else {
    int idx = (b - 500) * 64 + t;
    if (idx < 1250) {
      int oc = idx / 25, k = idx % 25;
      uint32_t m = 0;
      for (int ic = 0; ic < 20; ++ic)
        if (w2[(oc * 20 + ic) * 25 + k] > 0.f) m |= (1u << ic);
      wp2[idx] = m;
    }
  }
}

// Sum all 8192 images into T[1024]. 256 blocks x 32 images each.
__global__ __launch_bounds__(256) void sumT_k(const float* __restrict__ x,
                                              float* __restrict__ T) {
  int b = blockIdx.x, t = threadIdx.x;
  const float4* xv = (const float4*)x + (size_t)b * 32 * 256;
  float ax = 0.f, ay = 0.f, az = 0.f, aw = 0.f;
  for (int nn = 0; nn < 32; ++nn) {
    float4 v = xv[nn * 256 + t];
    ax += v.x; ay += v.y; az += v.z; aw += v.w;
  }
  atomicAdd(&T[t * 4 + 0], ax);
  atomicAdd(&T[t * 4 + 1], ay);
  atomicAdd(&T[t * 4 + 2], az);
  atomicAdd(&T[t * 4 + 3], aw);
}

// mean_c = (sum_tap w1[c][tap] * U[tap]) / (8192*784),
// U[tap] = valid-window sum of T.
__global__ void mean_k(const float* __restrict__ T, const float* __restrict__ w1,
                       float* __restrict__ mean) {
  __shared__ double U[25];
  int t = threadIdx.x;
  if (t < 25) {
    int ky = t / 5, kx = t % 5;
    double s = 0.0;
    for (int py = 0; py < 28; ++py)
      for (int px = 0; px < 28; ++px)
        s += (double)T[(py + ky) * 32 + px + kx];
    U[t] = s;
  }
  __syncthreads();
  if (t < 20) {
    double s = 0.0;
    for (int q = 0; q < 25; ++q) s += (double)w1[t * 25 + q] * U[q];
    mean[t] = (float)(s / (8192.0 * 784.0));
  }
}

// thread = (n, pooled pos). 6x6 patch in VGPRs, weights via SGPR (uniform idx).
__global__ __launch_bounds__(256) void conv1_sign_k(const float* __restrict__ x,
                                                    const float* __restrict__ w1,
                                                    const float* __restrict__ mean,
                                                    uint32_t* __restrict__ b1p) {
  unsigned gid = blockIdx.x * 256 + threadIdx.x;  // < 8192*196 exactly
  unsigned n = gid / 196u;
  unsigned pos = gid % 196u;
  unsigned py = pos / 14u, px = pos % 14u;
  const float* base = x + (size_t)n * 1024 + py * 64 + px * 2;
  float p[6][6];
#pragma unroll
  for (int r = 0; r < 6; ++r)
#pragma unroll
    for (int c = 0; c < 6; ++c)
      p[r][c] = base[r * 32 + c];
  uint32_t mask = 0;
  for (int c = 0; c < 20; ++c) {
    float s0 = 0.f, s1 = 0.f, s2 = 0.f, s3 = 0.f;
#pragma unroll
    for (int ky = 0; ky < 5; ++ky)
#pragma unroll
      for (int kx = 0; kx < 5; ++kx) {
        float wv = w1[c * 25 + ky * 5 + kx];  // uniform -> scalar load
        s0 += p[ky][kx] * wv;
        s1 += p[ky][kx + 1] * wv;
        s2 += p[ky + 1][kx] * wv;
        s3 += p[ky + 1][kx + 1] * wv;
      }
    float m = mean[c];
    if (s0 > m || s1 > m || s2 > m || s3 > m) mask |= (1u << c);
  }
  b1p[gid] = mask;
}

// Fused conv2 (binary popcount) + pool/sign + binary linear + fc. 1 block/image.
__global__ __launch_bounds__(256) void conv2lin_k(const uint32_t* __restrict__ b1p,
                                                  const uint32_t* __restrict__ wp2,
                                                  const unsigned long long* __restrict__ lwp,
                                                  const float* __restrict__ alpha,
                                                  const float* __restrict__ fcw,
                                                  const float* __restrict__ fcb,
                                                  float* __restrict__ out) {
  __shared__ uint32_t bm[196];
  __shared__ int sp[196];
  __shared__ int sumpc[100];
  __shared__ uint32_t wsh[1250];
  __shared__ signed char s2sh[1280];
  __shared__ unsigned long long Pm[20], Nm[20];
  __shared__ int cnts[2];
  __shared__ float hsh[512];
  __shared__ float fr[160];
  int n = blockIdx.x, tid = threadIdx.x;

  if (tid < 196) {
    uint32_t v = b1p[n * 196 + tid];
    bm[tid] = v;
    sp[tid] = __popc(v);
  }
  for (int i = tid; i < 1250; i += 256) wsh[i] = wp2[i];
  __syncthreads();
  if (tid < 100) {
    int y = tid / 10, xx = tid % 10, s = 0;
#pragma unroll
    for (int ky = 0; ky < 5; ++ky)
#pragma unroll
      for (int kx = 0; kx < 5; ++kx)
        s += sp[(y + ky) * 14 + xx + kx];
    sumpc[tid] = s;
  }
  __syncthreads();

  // conv2: thread = oc*5 + pooled_row
  if (tid < 250) {
    int oc = tid / 5, r = tid % 5;
    uint32_t w[25];
#pragma unroll
    for (int i = 0; i < 25; ++i) w[i] = wsh[oc * 25 + i];
    uint32_t pa[6][14];
#pragma unroll
    for (int rr = 0; rr < 6; ++rr)
      for (int cc = 0; cc < 14; ++cc)
        pa[rr][cc] = bm[(2 * r + rr) * 14 + cc];
    for (int c = 0; c < 5; ++c) {
      int best = -1000000;
#pragma unroll
      for (int dy = 0; dy < 2; ++dy)
#pragma unroll
        for (int dx = 0; dx < 2; ++dx) {
          int ux = 2 * c + dx;
          int a = 0;
#pragma unroll
          for (int ky = 0; ky < 5; ++ky)
#pragma unroll
            for (int kx = 0; kx < 5; ++kx)
              a += __popc(w[ky * 5 + kx] & pa[dy + ky][ux + kx]);
          a = 2 * a - sumpc[(2 * r + dy) * 10 + ux];
          if (a > best) best = a;
        }
      s2sh[oc * 25 + r * 5 + c] = (signed char)((best > 0) - (best < 0));
    }
  } else {
    // zero-pad 1250..1279 for the ballot pass
    for (int k = 0; k < 5; ++k) s2sh[1250 + (tid - 250) * 5 + k] = 0;
  }
  __syncthreads();

  // pack signs into P/N masks via ballot (lanes are consecutive indices)
  int wid = tid >> 6;
#pragma unroll
  for (int k = 0; k < 5; ++k) {
    int idx = k * 256 + tid;
    int v = s2sh[idx];
    unsigned long long P = __ballot(v > 0);
    unsigned long long N = __ballot(v < 0);
    if ((tid & 63) == 0) {
      int word = k * 4 + wid;
      if (word < 20) { Pm[word] = P; Nm[word] = N; }
    }
  }
  __syncthreads();
  if (tid == 0) {
    int cp = 0, cn = 0;
    for (int i = 0; i < 20; ++i) { cp += __popcll(Pm[i]); cn += __popcll(Nm[i]); }
    cnts[0] = cp; cnts[1] = cn;
  }
  __syncthreads();

  // binary linear 1250->500 + clip
  for (int j = tid; j < 500; j += 256) {
    const ulonglong2* W2 = (const ulonglong2*)(lwp + (size_t)j * 20);
    int a = 0, b = 0;
#pragma unroll
    for (int i = 0; i < 10; ++i) {
      ulonglong2 w2v = W2[i];
      a += __popcll(w2v.x & Pm[2 * i]) + __popcll(w2v.y & Pm[2 * i + 1]);
      b += __popcll(w2v.x & Nm[2 * i]) + __popcll(w2v.y & Nm[2 * i + 1]);
    }
    int dot = 2 * (a - b) - cnts[0] + cnts[1];
    float y = alpha[j] * (float)dot;
    hsh[j] = fminf(1.0f, fmaxf(-1.0f, y));
  }
  __syncthreads();

  // fc 500 -> 10
  if (tid < 160) {
    int o = tid >> 4, l = tid & 15;
    float pa = 0.f;
    for (int j = l; j < 500; j += 16) pa += hsh[j] * fcw[o * 500 + j];
    fr[tid] = pa;
  }
  __syncthreads();
  if (tid < 10) {
    float s = fcb[tid];
    for (int l = 0; l < 16; ++l) s += fr[tid * 16 + l];
    out[n * 10 + tid] = s;
  }
}

extern "C" void kernel_launch(void* const* d_in, const int* in_sizes, int n_in,
                              void* d_out, int out_size, void* d_ws, size_t ws_size,
                              hipStream_t stream) {
  const float* x   = (const float*)d_in[0];
  const float* w1  = (const float*)d_in[1];
  const float* w2  = (const float*)d_in[2];
  const float* lw  = (const float*)d_in[3];
  const float* fcw = (const float*)d_in[4];
  const float* fcb = (const float*)d_in[5];
  float* out = (float*)d_out;
  char* ws = (char*)d_ws;

  float*    T     = (float*)(ws + 0);
  float*    mean  = (float*)(ws + 4096);
  uint32_t* wp2   = (uint32_t*)(ws + 4224);
  float*    alpha = (float*)(ws + 9344);
  unsigned long long* lwp = (unsigned long long*)(ws + 11392);
  uint32_t* b1p   = (uint32_t*)(ws + 91392);

  hipMemsetAsync(T, 0, 1024 * sizeof(float), stream);
  prep_k<<<520, 64, 0, stream>>>(lw, w2, lwp, alpha, wp2);
  sumT_k<<<256, 256, 0, stream>>>(x, T);
  mean_k<<<1, 64, 0, stream>>>(T, w1, mean);
  conv1_sign_k<<<NIMG * 196 / 256, 256, 0, stream>>>(x, w1, mean, b1p);
  conv2lin_k<<<NIMG, 256, 0, stream>>>(b1p, wp2, lwp, alpha, fcw, fcb, out);
}